// Round 2
// baseline (1067.708 us; speedup 1.0000x reference)
//
#include <hip/hip_runtime.h>
#include <math.h>

#define MULT 32
#define NSPEC 10
#define NGRAPH 16
#define INV_SC 0.05590169943749474f   /* 1/sqrt(32*10) */
#define INV32S 0.17677669529663687f   /* 1/sqrt(32) */

typedef unsigned short u16;
typedef __bf16 v8bf __attribute__((ext_vector_type(8)));
typedef float v4f __attribute__((ext_vector_type(4)));
typedef unsigned int v4u_t __attribute__((ext_vector_type(4)));

__device__ __forceinline__ u16 f2bf(float f) {
    unsigned int u = __builtin_bit_cast(unsigned int, f);
    unsigned int r = u + 0x7fffu + ((u >> 16) & 1u);
    return (u16)(r >> 16);
}

__device__ __forceinline__ v8bf frag16(const u16* p) {
    return __builtin_bit_cast(v8bf, *(const v4u_t*)p);
}

#define MFMA(a, b, c) __builtin_amdgcn_mfma_f32_16x16x32_bf16(a, b, c, 0, 0, 0)

// ---------------------------------------------------------------------------
// small utility kernels
// ---------------------------------------------------------------------------
__global__ void zero_kernel(float* __restrict__ p, int n) {
    int i = blockIdx.x * 256 + threadIdx.x;
    if (i < n) p[i] = 0.0f;
}

__global__ void count_kernel(const int* __restrict__ batch, float* __restrict__ cnt, int N) {
    __shared__ int bins[NGRAPH];
    int t = threadIdx.x;
    if (t < NGRAPH) bins[t] = 0;
    __syncthreads();
    int i = blockIdx.x * 256 + t;
    if (i < N) atomicAdd(&bins[batch[i]], 1);
    __syncthreads();
    if (t < NGRAPH && bins[t] > 0) atomicAdd(&cnt[t], (float)bins[t]);
}

// ---------------------------------------------------------------------------
// effective-weight precompute (fp32), as round 1:
//  Weff[path,b][a,bb,z], path: 0=000, 1=110, 2=011, 3=101
// ---------------------------------------------------------------------------
__global__ void stageA_kernel(const float* __restrict__ w000, const float* __restrict__ w110,
                              const float* __restrict__ w011, const float* __restrict__ w101,
                              const float* __restrict__ lp0, const float* __restrict__ lp1,
                              float* __restrict__ tmp1) {
    int gid = blockIdx.x * 256 + threadIdx.x;
    int tslot = gid >> 15;
    int e = gid & 32767;
    int z = e & 31;
    int uv = e >> 5;
    int b = tslot >> 2, path = tslot & 3;
    const float* W = (path == 0 ? w000 : path == 1 ? w110 : path == 2 ? w011 : w101) + b * 32768;
    const float* L = ((path == 0 || path == 1) ? lp0 : lp1) + b * 1024;
    float scale = (path == 1) ? (1.0f / (8192.0f * 1.7320508075688772f)) : (1.0f / 8192.0f);
    const float* wr = W + uv * 32;
    float acc = 0.0f;
    for (int w = 0; w < 32; ++w) acc += wr[w] * L[w * 32 + z];
    tmp1[gid] = acc * scale;
}

__global__ void stageB_kernel(const float* __restrict__ ul0, const float* __restrict__ ul1,
                              const float* __restrict__ tmp1, float* __restrict__ tmp2) {
    int gid = blockIdx.x * 256 + threadIdx.x;
    int tslot = gid >> 15;
    int e = gid & 32767;
    int z = e & 31;
    int bb = (e >> 5) & 31;
    int u = e >> 10;
    int b = tslot >> 2, path = tslot & 3;
    const float* U = ((path == 0 || path == 3) ? ul0 : ul1) + b * 1024;
    const float* in = tmp1 + (size_t)tslot * 32768 + u * 1024 + z;
    float acc = 0.0f;
    for (int v = 0; v < 32; ++v) acc += U[bb * 32 + v] * in[v * 32];
    tmp2[gid] = acc;
}

__global__ void stageC_kernel(const float* __restrict__ hl0, const float* __restrict__ hl1,
                              const float* __restrict__ tmp2, float* __restrict__ Weff) {
    int gid = blockIdx.x * 256 + threadIdx.x;
    int tslot = gid >> 15;
    int e = gid & 32767;
    int z = e & 31;
    int bb = (e >> 5) & 31;
    int a = e >> 10;
    int b = tslot >> 2, path = tslot & 3;
    const float* H = ((path == 0 || path == 2) ? hl0 : hl1) + b * 1024;
    const float* in = tmp2 + (size_t)tslot * 32768 + bb * 32 + z;
    float acc = 0.0f;
    for (int u = 0; u < 32; ++u) acc += H[a * 32 + u] * in[u * 1024];
    Weff[gid] = acc;
}

// ---------------------------------------------------------------------------
// pack kernel: fp32 Weff / sc weights -> bf16, B-frag-friendly transposed
// per-b flat layout (155648 u16):
//  [0,32768):       W000T[col=bb*32+z][a]
//  [32768,65536):   W011T[col=bb*32+z][a]
//  [65536,98304):   W101T[col=a*32+z][bb]
//  [98304,131072):  W110T[z][k=a*32+bb]
//  [131072,143360): WSC0T[z][ku=u*10+s, pad to 384]  (x INV_SC)
//  [143360,155648): WSC1T[z][ku]                      (x INV_SC)
// ---------------------------------------------------------------------------
__global__ void pack_kernel(const float* __restrict__ Weff,
                            const float* __restrict__ sc_w0, const float* __restrict__ sc_w1,
                            u16* __restrict__ packs, int total) {
    int gid = blockIdx.x * 256 + threadIdx.x;
    if (gid >= total) return;
    int b = gid / 155648;
    int e = gid - b * 155648;
    float v;
    if (e < 98304) {
        int which = e >> 15;          // 0:000  1:011  2:101
        int e2 = e & 32767;
        int col = e2 >> 5, k = e2 & 31;
        int path = (which == 0) ? 0 : (which == 1) ? 2 : 3;
        int a, bb, z;
        if (which < 2) { a = k; bb = col >> 5; z = col & 31; }
        else           { bb = k; a = col >> 5; z = col & 31; }
        v = Weff[(size_t)((b * 4 + path) * 32 + a) * 1024 + bb * 32 + z];
    } else if (e < 131072) {
        int e2 = e - 98304;
        int z = e2 >> 10, k = e2 & 1023, a = k >> 5, bb = k & 31;
        v = Weff[(size_t)((b * 4 + 1) * 32 + a) * 1024 + bb * 32 + z];
    } else {
        int e2 = e - 131072;
        int which = e2 / 12288; int e3 = e2 - which * 12288;
        int z = e3 / 384, ku = e3 - z * 384;
        if (ku < 320) {
            int u = ku / 10, s = ku - u * 10;
            const float* S = which ? sc_w1 : sc_w0;
            v = S[(size_t)b * 10240 + u * 320 + s * 32 + z] * INV_SC;
        } else v = 0.0f;
    }
    packs[gid] = f2bf(v);
}

// ---------------------------------------------------------------------------
// device helpers for tp kernel
// ---------------------------------------------------------------------------
__device__ __forceinline__ void gemm_f1(const u16* __restrict__ Wt, v8bf afrag,
                                        int w, int quad, int c16, v4f (&C)[16]) {
#pragma unroll
    for (int t16 = 0; t16 < 16; ++t16) {
        const u16* bp = Wt + (w * 256 + t16 * 16 + c16) * 32 + quad * 8;
        v8bf bfrag = frag16(bp);
        v4f z4 = {0.f, 0.f, 0.f, 0.f};
        C[t16] = MFMA(afrag, bfrag, z4);
    }
}

__device__ __forceinline__ void st2(const float* __restrict__ YT, int w, int quad,
                                    float (&acc)[2][4], const v4f (&C)[16]) {
#pragma unroll
    for (int t16 = 0; t16 < 16; ++t16) {
        v4f y = *(const v4f*)(YT + (w * 8 + (t16 >> 1)) * 16 + quad * 4);
#pragma unroll
        for (int r = 0; r < 4; ++r) acc[t16 & 1][r] += C[t16][r] * y[r];
    }
}

__device__ __forceinline__ void buildA(u16* __restrict__ Ap, const u16* __restrict__ X,
                                       const int* __restrict__ spec_l, int t) {
    int n = t >> 4, seg = t & 15, s = spec_l[n];
    u16* row = Ap + n * 392;
    const u16* xr = X + n * 40;
    int e0 = seg * 25, e1 = (e0 + 25 < 392) ? e0 + 25 : 392;
    for (int e = e0; e < e1; ++e) {
        int u = e / 10;
        row[e] = (e < 320 && (e - u * 10) == s) ? xr[u] : (u16)0;
    }
}

__device__ __forceinline__ void gemm_sc(const u16* __restrict__ Wt, const u16* __restrict__ Ap,
                                        int w, int quad, int c16, float (&acc)[2][4]) {
    v4f a0 = {0.f, 0.f, 0.f, 0.f}, a1 = {0.f, 0.f, 0.f, 0.f};
#pragma unroll
    for (int kk = 0; kk < 3; ++kk) {
        int ko = w * 96 + kk * 32 + quad * 8;
        v8bf af = frag16(Ap + c16 * 392 + ko);
        v8bf b0 = frag16(Wt + c16 * 384 + ko);
        v8bf b1 = frag16(Wt + (16 + c16) * 384 + ko);
        a0 = MFMA(af, b0, a0);
        a1 = MFMA(af, b1, a1);
    }
#pragma unroll
    for (int r = 0; r < 4; ++r) { acc[0][r] += a0[r]; acc[1][r] += a1[r]; }
}

// ---------------------------------------------------------------------------
// MFMA TP + self-connection + stats kernel.  One WG (4 waves) per 16 nodes.
// ---------------------------------------------------------------------------
__global__ __launch_bounds__(256, 2)
void tp_kernel(const float* __restrict__ hidden_b, const float* __restrict__ up,
               const u16* __restrict__ W000T, const u16* __restrict__ W011T,
               const u16* __restrict__ W101T, const u16* __restrict__ W110T,
               const u16* __restrict__ WSC0T, const u16* __restrict__ WSC1T,
               const float* __restrict__ lp_b0,
               const int* __restrict__ species, const int* __restrict__ batch,
               float* __restrict__ S1, float* __restrict__ S2, float* __restrict__ V2,
               float* __restrict__ zout, int N) {
    __shared__ __align__(16) u16 sh_bf[16][40];      // +8 pad: 2-way banks for A-frags
    __shared__ __align__(16) u16 su_bf[16][40];
    __shared__ __align__(16) u16 vh_bf[3][16][40];
    __shared__ __align__(16) float suT[32][16];      // Y operands, transposed fp32
    __shared__ __align__(16) float vuT[3][32][16];
    __shared__ __align__(16) float vhT[3][32][16];
    __shared__ __align__(16) u16 Pm[16][1064];       // P matrix; overlaid by red later
    __shared__ __align__(16) u16 Ap[16][392];        // one-hot expanded SC A-matrix
    __shared__ __align__(16) float zb[16][128];
    __shared__ int spec_l[16];
    __shared__ int bat_l[16];
    __shared__ float gs1[NGRAPH], gs2[NGRAPH], gv2[NGRAPH];

    const int t = threadIdx.x;
    const int w = t >> 6, lane = t & 63, quad = lane >> 4, c16 = lane & 15;
    const int n0 = blockIdx.x * 16;
    const int nvalid = min(16, N - n0);

    // ---- phase 0: load node tile ----
    for (int i = t; i < 2048; i += 256) {
        int n = i >> 7, col = i & 127;
        float hv = 0.f, uv = 0.f;
        if (n < nvalid) {
            hv = hidden_b[(size_t)(n0 + n) * 128 + col];
            uv = up[(size_t)(n0 + n) * 128 + col];
        }
        if (col < 32) {
            sh_bf[n][col] = f2bf(hv); su_bf[n][col] = f2bf(uv);
            suT[col][n] = uv;
        } else {
            int idx = col - 32, c = idx % 3, a = idx / 3;
            vh_bf[c][n][a] = f2bf(hv);
            vhT[c][a][n] = hv; vuT[c][a][n] = uv;
        }
    }
    if (t < 16) {
        spec_l[t] = (t < nvalid) ? species[n0 + t] : 0;
        bat_l[t]  = (t < nvalid) ? batch[n0 + t] : 0;
    }
    __syncthreads();

    // ---- phase 0b: P build (for 110) + A'(sh) build (for SC scalar) ----
    {
        int n = t >> 4, seg = t & 15;
        unsigned int* prow = (unsigned int*)&Pm[n][0];
        for (int e = seg * 64; e < seg * 64 + 64; e += 2) {
            int a = e >> 5, bb = e & 31;
            float p0 = 0.f, p1 = 0.f;
#pragma unroll
            for (int c = 0; c < 3; ++c) {
                float hv = vhT[c][a][n];
                p0 += hv * vuT[c][bb][n];
                p1 += hv * vuT[c][bb + 1][n];
            }
            prow[e >> 1] = (unsigned int)f2bf(p0) | ((unsigned int)f2bf(p1) << 16);
        }
    }
    buildA(&Ap[0][0], &sh_bf[0][0], spec_l, t);
    __syncthreads();

    v8bf a_sh = frag16(&sh_bf[c16][quad * 8]);
    v8bf a_su = frag16(&su_bf[c16][quad * 8]);
    float z0a[2][4] = {};
    float z1a[3][2][4] = {};

    // ---- path 000: T = sh @ W000, stage2 with su ----
    {
        v4f C[16];
        gemm_f1(W000T, a_sh, w, quad, c16, C);
        st2(&suT[0][0], w, quad, z0a, C);
    }
    // ---- path 011: T = sh @ W011, stage2 with vu[c] x3 ----
    {
        v4f C[16];
        gemm_f1(W011T, a_sh, w, quad, c16, C);
#pragma unroll
        for (int c = 0; c < 3; ++c) st2(&vuT[c][0][0], w, quad, z1a[c], C);
    }
    // ---- path 101: T = su @ W101, stage2 with vh[c] x3 ----
    {
        v4f C[16];
        gemm_f1(W101T, a_su, w, quad, c16, C);
#pragma unroll
        for (int c = 0; c < 3; ++c) st2(&vhT[c][0][0], w, quad, z1a[c], C);
    }
    // ---- path 110: z0 += P @ W110flat (K=1024, K-split over waves) ----
    {
        v4f a0 = {0.f, 0.f, 0.f, 0.f}, a1 = {0.f, 0.f, 0.f, 0.f};
#pragma unroll
        for (int kk = 0; kk < 8; ++kk) {
            int ko = w * 256 + kk * 32 + quad * 8;
            v8bf af = frag16(&Pm[c16][ko]);
            v8bf b0 = frag16(W110T + c16 * 1024 + ko);
            v8bf b1 = frag16(W110T + (16 + c16) * 1024 + ko);
            a0 = MFMA(af, b0, a0);
            a1 = MFMA(af, b1, a1);
        }
#pragma unroll
        for (int r = 0; r < 4; ++r) { z0a[0][r] += a0[r]; z0a[1][r] += a1[r]; }
    }
    // ---- self connection scalar (A' from sh already built) ----
    gemm_sc(WSC0T, &Ap[0][0], w, quad, c16, z0a);
    // ---- self connection vector x3 ----
    for (int c = 0; c < 3; ++c) {
        __syncthreads();
        buildA(&Ap[0][0], &vh_bf[c][0][0], spec_l, t);
        __syncthreads();
        gemm_sc(WSC1T, &Ap[0][0], w, quad, c16, z1a[c]);
    }

    // ---- epilogue: cross-wave reduce (red overlays Pm) ----
    float* redf = (float*)&Pm[0][0];   // [4][16][132]
    __syncthreads();
#pragma unroll
    for (int r = 0; r < 4; ++r) {
        int n = quad * 4 + r;
        float* rw = redf + (w * 16 + n) * 132;
        rw[c16] = z0a[0][r];
        rw[16 + c16] = z0a[1][r];
#pragma unroll
        for (int c = 0; c < 3; ++c) {
            rw[32 + c16 * 3 + c] = z1a[c][0][r];
            rw[32 + (16 + c16) * 3 + c] = z1a[c][1][r];
        }
    }
    __syncthreads();
    for (int i = t; i < 2048; i += 256) {
        int n = i >> 7, ch = i & 127;
        float s = redf[(0 * 16 + n) * 132 + ch] + redf[(1 * 16 + n) * 132 + ch]
                + redf[(2 * 16 + n) * 132 + ch] + redf[(3 * 16 + n) * 132 + ch];
        if (ch < 32) s += lp_b0[ch];
        zb[n][ch] = s;
    }
    __syncthreads();

    // ---- per-graph stats ----
    if (t < NGRAPH) { gs1[t] = 0.f; gs2[t] = 0.f; gv2[t] = 0.f; }
    if (t < 64) {
        int n = t >> 2, q = t & 3;
        float s1 = 0.f, s2 = 0.f, v2 = 0.f;
#pragma unroll
        for (int k = 0; k < 8; ++k) { float x = zb[n][q * 8 + k]; s1 += x; s2 += x * x; }
#pragma unroll
        for (int k = 0; k < 24; ++k) { float x = zb[n][32 + q * 24 + k]; v2 += x * x; }
        redf[q * 512 + n * 32 + 0] = s1;
        redf[q * 512 + n * 32 + 1] = s2;
        redf[q * 512 + n * 32 + 2] = v2;
    }
    __syncthreads();
    if (t < 16 && t < nvalid) {
        float s1 = redf[t * 32 + 0] + redf[512 + t * 32 + 0] + redf[1024 + t * 32 + 0] + redf[1536 + t * 32 + 0];
        float s2 = redf[t * 32 + 1] + redf[512 + t * 32 + 1] + redf[1024 + t * 32 + 1] + redf[1536 + t * 32 + 1];
        float v2 = redf[t * 32 + 2] + redf[512 + t * 32 + 2] + redf[1024 + t * 32 + 2] + redf[1536 + t * 32 + 2];
        int g = bat_l[t];
        atomicAdd(&gs1[g], s1); atomicAdd(&gs2[g], s2); atomicAdd(&gv2[g], v2);
    }
    __syncthreads();
    if (t < NGRAPH) {
        if (gs1[t] != 0.f) atomicAdd(&S1[t], gs1[t]);
        if (gs2[t] != 0.f) atomicAdd(&S2[t], gs2[t]);
        if (gv2[t] != 0.f) atomicAdd(&V2[t], gv2[t]);
    }

    // ---- store pre-norm z ----
    const float* zbf = &zb[0][0];
    for (int i = t; i < nvalid * 128; i += 256)
        zout[(size_t)n0 * 128 + i] = zbf[i];
}

// ---------------------------------------------------------------------------
// LayerNorm + skip kernel (in-place on z written by tp_kernel) — as round 1
// ---------------------------------------------------------------------------
__global__ __launch_bounds__(256)
void norm_kernel(const float* __restrict__ hidden_b, float* __restrict__ out_b,
                 const float* __restrict__ skw0, const float* __restrict__ skb0,
                 const float* __restrict__ skw1,
                 const float* __restrict__ lnw0, const float* __restrict__ lnb0,
                 const float* __restrict__ lnw1,
                 const int* __restrict__ batch,
                 const float* __restrict__ S1, const float* __restrict__ S2,
                 const float* __restrict__ V2, const float* __restrict__ cnt, int N) {
    __shared__ __align__(16) float sh_l[8][32];
    __shared__ __align__(16) float vh_l[8][96];
    const int t = threadIdx.x, z = t & 31, nl = t >> 5;
    const int n0 = blockIdx.x * 8;
    for (int i = t; i < 8 * 128; i += 256) {
        int n = i >> 7, col = i & 127;
        float v = (n0 + n < N) ? hidden_b[(size_t)(n0 + n) * 128 + col] : 0.f;
        if (col < 32) sh_l[n][col] = v; else vh_l[n][col - 32] = v;
    }
    __syncthreads();
    const int n = n0 + nl;
    if (n >= N) return;

    float sk0 = 0.f, s1 = 0.f, s2 = 0.f, s3 = 0.f;
    for (int a = 0; a < 32; ++a) {
        float w0 = skw0[a * 32 + z];
        float w1 = skw1[a * 32 + z];
        sk0 += sh_l[nl][a] * w0;
        s1 += vh_l[nl][a * 3 + 0] * w1;
        s2 += vh_l[nl][a * 3 + 1] * w1;
        s3 += vh_l[nl][a * 3 + 2] * w1;
    }
    int g = batch[n];
    float cM = fmaxf(cnt[g], 1.0f) * 32.0f;
    float mean = S1[g] / cM;
    float var = fmaxf(S2[g] / cM - mean * mean, 0.0f);
    float rs = rsqrtf(var + 1e-5f);
    float rv = rsqrtf(fmaxf(V2[g] / cM, 0.0f) + 1e-5f);

    size_t base = (size_t)n * 128;
    float z0 = out_b[base + z];
    out_b[base + z] = (z0 - mean) * rs * lnw0[z] + lnb0[z] + sk0 * INV32S + skb0[z];
    float lw = lnw1[z] * rv;
    float x0 = out_b[base + 32 + z * 3 + 0];
    float x1 = out_b[base + 32 + z * 3 + 1];
    float x2 = out_b[base + 32 + z * 3 + 2];
    out_b[base + 32 + z * 3 + 0] = x0 * lw + s1 * INV32S;
    out_b[base + 32 + z * 3 + 1] = x1 * lw + s2 * INV32S;
    out_b[base + 32 + z * 3 + 2] = x2 * lw + s3 * INV32S;
}

// ---------------------------------------------------------------------------
extern "C" void kernel_launch(void* const* d_in, const int* in_sizes, int n_in,
                              void* d_out, int out_size, void* d_ws, size_t ws_size,
                              hipStream_t stream) {
    const float* hidden = (const float*)d_in[0];
    const float* up0    = (const float*)d_in[1];
    const float* hl_w0  = (const float*)d_in[2];
    const float* hl_w1  = (const float*)d_in[3];
    const float* ul_w0  = (const float*)d_in[4];
    const float* ul_w1  = (const float*)d_in[5];
    const float* w000   = (const float*)d_in[6];
    const float* w110   = (const float*)d_in[7];
    const float* w011   = (const float*)d_in[8];
    const float* w101   = (const float*)d_in[9];
    const float* lp_w0  = (const float*)d_in[10];
    const float* lp_b0  = (const float*)d_in[11];
    const float* lp_w1  = (const float*)d_in[12];
    const float* sc_w0  = (const float*)d_in[13];
    const float* sc_w1  = (const float*)d_in[14];
    const float* ln_w0  = (const float*)d_in[15];
    const float* ln_b0  = (const float*)d_in[16];
    const float* ln_w1  = (const float*)d_in[17];
    const float* sk_w0  = (const float*)d_in[18];
    const float* sk_b0  = (const float*)d_in[19];
    const float* sk_w1  = (const float*)d_in[20];
    const int* species  = (const int*)d_in[21];
    const int* batch    = (const int*)d_in[22];
    float* out = (float*)d_out;

    const int N = in_sizes[21];
    const int B = in_sizes[0] / (N * 128);

    float* ws = (float*)d_ws;
    float* Weff = ws;                                  // B*4*32768 fp32
    float* tmp1 = Weff + (size_t)B * 4 * 32768;        // reused as bf16 packs
    float* tmp2 = tmp1 + (size_t)B * 4 * 32768;
    float* stats = tmp2 + (size_t)B * 4 * 32768;
    float* cnt = stats;
    float* S1 = stats + NGRAPH;
    float* S2 = S1 + B * NGRAPH;
    float* V2 = S2 + B * NGRAPH;
    int statn = NGRAPH + 3 * B * NGRAPH;

    zero_kernel<<<1, 256, 0, stream>>>(stats, statn);
    count_kernel<<<(N + 255) / 256, 256, 0, stream>>>(batch, cnt, N);

    int nb = B * 4 * 32768 / 256;
    stageA_kernel<<<nb, 256, 0, stream>>>(w000, w110, w011, w101, lp_w0, lp_w1, tmp1);
    stageB_kernel<<<nb, 256, 0, stream>>>(ul_w0, ul_w1, tmp1, tmp2);
    stageC_kernel<<<nb, 256, 0, stream>>>(hl_w0, hl_w1, tmp2, Weff);

    u16* packs = (u16*)tmp1;                           // tmp1 dead after stageB
    int ptotal = B * 155648;
    pack_kernel<<<(ptotal + 255) / 256, 256, 0, stream>>>(Weff, sc_w0, sc_w1, packs, ptotal);

    for (int b = 0; b < B; ++b) {
        const float* up = (b == 0) ? up0 : out + (size_t)(b - 1) * N * 128;
        const u16* pb = packs + (size_t)b * 155648;
        tp_kernel<<<(N + 15) / 16, 256, 0, stream>>>(
            hidden + (size_t)b * N * 128, up,
            pb, pb + 32768, pb + 65536, pb + 98304, pb + 131072, pb + 143360,
            lp_b0 + b * MULT, species, batch,
            S1 + b * NGRAPH, S2 + b * NGRAPH, V2 + b * NGRAPH,
            out + (size_t)b * N * 128, N);
        norm_kernel<<<(N + 7) / 8, 256, 0, stream>>>(
            hidden + (size_t)b * N * 128, out + (size_t)b * N * 128,
            sk_w0 + b * 1024, sk_b0 + b * MULT, sk_w1 + b * 1024,
            ln_w0 + b * MULT, ln_b0 + b * MULT, ln_w1 + b * MULT,
            batch, S1 + b * NGRAPH, S2 + b * NGRAPH, V2 + b * NGRAPH, cnt, N);
    }
}